// Round 2
// baseline (189.860 us; speedup 1.0000x reference)
//
#include <hip/hip_runtime.h>

// Problem constants (match reference)
#define NB 32
#define CH 3
#define HH 768
#define WW 768

// Tiling
#define TW 64            // output tile width
#define TH 32            // output tile height
#define SW 72            // staged width: [tw0-4, tw0+68), 16B aligned both sides
#define SH (TH + 4)      // 36 staged rows: [th0-2, th0+34)
#define RX 4             // outputs per thread in w (float4 stores)
#define RY 2             // outputs per thread in h
// 256 threads = 16 across (64/4) x 16 down (32/2)

__global__ __launch_bounds__(256) void colwarp_conv_kernel(
    const float* __restrict__ im,
    const float* __restrict__ flat,
    float* __restrict__ out)
{
    const int tilesW = WW / TW;                 // 12
    const int tile   = blockIdx.x;              // 0..287
    const int b      = blockIdx.y;              // 0..31
    const int tw0    = (tile % tilesW) * TW;
    const int th0    = (tile / tilesW) * TH;

    // 3 * 36 * 72 * 4B = 31104 B -> 5 blocks/CU
    __shared__ float xs[CH][SH][SW];

    const int tid = threadIdx.x;

    // ---- per-sample params (uniform address -> scalar loads) ----
    const float* f = flat + b * 37;
    float Wm[3][3];
#pragma unroll
    for (int d = 0; d < 3; ++d)
#pragma unroll
        for (int c = 0; c < 3; ++c)
            Wm[d][c] = f[d * 3 + c];

    float sh[3];
#pragma unroll
    for (int d = 0; d < 3; ++d) sh[d] = f[9 + d];

    float K[5][5];
#pragma unroll
    for (int i = 0; i < 5; ++i)
#pragma unroll
        for (int j = 0; j < 5; ++j)
            K[i][j] = f[12 + i * 5 + j];

    // ---- stage RAW channels (+ per-channel shift), zero-padded, all float4 ----
    // out_c = sum_d Wm[d][c] * conv5(im_d + sh_d)  (mix commutes with conv;
    // shift stays inside staging so zero-padding semantics match reference).
    const size_t plane = (size_t)HH * WW;
    const float* im0 = im + (size_t)b * CH * plane;

#pragma unroll
    for (int ch = 0; ch < CH; ++ch) {
        const float* ip = im0 + (size_t)ch * plane;
        const float s = sh[ch];
        for (int u = tid; u < SH * (SW / 4); u += 256) {   // 36*18 = 648 float4 units
            const int r  = u / (SW / 4);
            const int c4 = u - r * (SW / 4);
            const int gh = th0 + r - 2;
            const int gw = tw0 - 4 + c4 * 4;               // float4 never straddles image edge
            float4 v = make_float4(0.f, 0.f, 0.f, 0.f);
            if ((unsigned)gh < (unsigned)HH && (unsigned)gw < (unsigned)WW) {
                v = *(const float4*)(ip + (size_t)gh * WW + gw);
                v.x += s; v.y += s; v.z += s; v.w += s;
            }
            *(float4*)&xs[ch][r][c4 * 4] = v;
        }
    }
    __syncthreads();

    // ---- conv 5x5 per raw channel from LDS, register-blocked RX x RY ----
    const int tx = tid & 15;   // 0..15, 4 output cols each
    const int ty = tid >> 4;   // 0..15, 2 output rows each
    const int r0 = ty * RY;

    float acc[CH][RY][RX];
#pragma unroll
    for (int c = 0; c < CH; ++c)
#pragma unroll
        for (int r = 0; r < RY; ++r)
#pragma unroll
            for (int o = 0; o < RX; ++o)
                acc[c][r][o] = 0.f;

#pragma unroll
    for (int rr = 0; rr < RY + 4; ++rr) {
#pragma unroll
        for (int c = 0; c < CH; ++c) {
            // need staged floats [4tx+2 .. 4tx+9] of row r0+rr (8B aligned -> ds_read2_b64)
            const float2* rp = (const float2*)&xs[c][r0 + rr][2 + tx * RX];
            const float2 p0 = rp[0], p1 = rp[1], p2 = rp[2], p3 = rp[3];
            const float w8[8] = {p0.x, p0.y, p1.x, p1.y, p2.x, p2.y, p3.x, p3.y};
#pragma unroll
            for (int i = 0; i < 5; ++i) {
                const int r = rr - i;
                if (r >= 0 && r < RY) {
#pragma unroll
                    for (int j = 0; j < 5; ++j) {
#pragma unroll
                        for (int o = 0; o < RX; ++o)
                            acc[c][r][o] += w8[o + j] * K[i][j];
                    }
                }
            }
        }
    }

    // ---- epilogue: 3x3 mix per output pixel, float4 stores ----
#pragma unroll
    for (int r = 0; r < RY; ++r) {
        float4 vc[CH];
#pragma unroll
        for (int c = 0; c < CH; ++c) {
            const float d0 = acc[0][r][0] * Wm[0][c] + acc[1][r][0] * Wm[1][c] + acc[2][r][0] * Wm[2][c];
            const float d1 = acc[0][r][1] * Wm[0][c] + acc[1][r][1] * Wm[1][c] + acc[2][r][1] * Wm[2][c];
            const float d2 = acc[0][r][2] * Wm[0][c] + acc[1][r][2] * Wm[1][c] + acc[2][r][2] * Wm[2][c];
            const float d3 = acc[0][r][3] * Wm[0][c] + acc[1][r][3] * Wm[1][c] + acc[2][r][3] * Wm[2][c];
            vc[c] = make_float4(d0, d1, d2, d3);
        }
#pragma unroll
        for (int c = 0; c < CH; ++c) {
            float* ob = out + ((size_t)b * CH + c) * plane;
            *(float4*)&ob[(size_t)(th0 + r0 + r) * WW + tw0 + tx * RX] = vc[c];
        }
    }
}

extern "C" void kernel_launch(void* const* d_in, const int* in_sizes, int n_in,
                              void* d_out, int out_size, void* d_ws, size_t ws_size,
                              hipStream_t stream) {
    const float* im   = (const float*)d_in[0];
    const float* flat = (const float*)d_in[1];
    float* out        = (float*)d_out;

    dim3 grid((WW / TW) * (HH / TH), NB);  // (288, 32)
    colwarp_conv_kernel<<<grid, 256, 0, stream>>>(im, flat, out);
}